// Round 1
// baseline (762.757 us; speedup 1.0000x reference)
//
#include <hip/hip_runtime.h>

#define N_NODES 50000
#define N_EDGES 600000
#define DIM 128
#define N_LAYERS 4
#define N_GRAPHS 64
#define NEG_SLOPE 0.01f

// ---------------- utility kernels ----------------

__global__ void zero_ints(int* p, int n) {
    int i = blockIdx.x * blockDim.x + threadIdx.x;
    if (i < n) p[i] = 0;
}

// transpose all 4 layers of Wl and Wr: WT[l][k][j] = W[l][j][k]
__global__ void transpose_w(const float* __restrict__ Wl, const float* __restrict__ Wr,
                            float* __restrict__ WlT, float* __restrict__ WrT) {
    __shared__ float tile[32][33];
    int z = blockIdx.z;  // 0..7 : 0-3 Wl layers, 4-7 Wr layers
    const float* src = (z < 4) ? (Wl + z * DIM * DIM) : (Wr + (z - 4) * DIM * DIM);
    float* dst = (z < 4) ? (WlT + z * DIM * DIM) : (WrT + (z - 4) * DIM * DIM);
    int k0 = blockIdx.x * 32, j0 = blockIdx.y * 32;
    int tx = threadIdx.x, ty = threadIdx.y;  // block (32,8)
    for (int r = 0; r < 32; r += 8)
        tile[ty + r][tx] = src[(j0 + ty + r) * DIM + k0 + tx];
    __syncthreads();
    for (int r = 0; r < 32; r += 8)
        dst[(k0 + ty + r) * DIM + j0 + tx] = tile[tx][ty + r];
}

__global__ void count_deg(const int* __restrict__ dst, int* deg) {
    int e = blockIdx.x * blockDim.x + threadIdx.x;
    if (e < N_EDGES) atomicAdd(&deg[dst[e]], 1);
}

// single-block inclusive scan -> row_ptr (exclusive layout: rp[0]=0, rp[i+1]=sum<=i)
__global__ void scan_deg(const int* __restrict__ deg, int* __restrict__ rp) {
    __shared__ int sm[1024];
    __shared__ int carry;
    if (threadIdx.x == 0) { carry = 0; rp[0] = 0; }
    __syncthreads();
    for (int base = 0; base < N_NODES; base += 1024) {
        int i = base + threadIdx.x;
        int v = (i < N_NODES) ? deg[i] : 0;
        sm[threadIdx.x] = v;
        __syncthreads();
        for (int off = 1; off < 1024; off <<= 1) {
            int t = (threadIdx.x >= off) ? sm[threadIdx.x - off] : 0;
            __syncthreads();
            sm[threadIdx.x] += t;
            __syncthreads();
        }
        if (i < N_NODES) rp[i + 1] = carry + sm[threadIdx.x];
        __syncthreads();
        if (threadIdx.x == 0) carry += sm[1023];
        __syncthreads();
    }
}

__global__ void fill_csr(const int* __restrict__ src, const int* __restrict__ dst,
                         const int* __restrict__ rp, int* __restrict__ fill,
                         int* __restrict__ csr) {
    int e = blockIdx.x * blockDim.x + threadIdx.x;
    if (e >= N_EDGES) return;
    int d = dst[e];
    int pos = atomicAdd(&fill[d], 1);
    csr[rp[d] + pos] = src[e];
}

// graph segment starts from sorted batch vector
__global__ void graph_start(const int* __restrict__ batch, int* __restrict__ gstart) {
    int i = blockIdx.x * blockDim.x + threadIdx.x;
    if (i >= N_NODES) return;
    int b = batch[i];
    if (i == 0) {
        for (int g = 0; g <= b; g++) gstart[g] = 0;
    } else {
        int p = batch[i - 1];
        for (int g = p + 1; g <= b; g++) gstart[g] = i;
    }
    if (i == N_NODES - 1) {
        for (int g = b + 1; g <= N_GRAPHS; g++) gstart[g] = N_NODES;
    }
}

// ---------------- aggregation: mean over in-neighbors via CSR gather ----------------
// 8 nodes per 256-thread block; 32 lanes per node, float4 per lane.
__global__ __launch_bounds__(256) void agg_mean(const float4* __restrict__ x4,
                                                const int* __restrict__ rp,
                                                const int* __restrict__ csr,
                                                float4* __restrict__ agg4) {
    int node = blockIdx.x * 8 + (threadIdx.x >> 5);
    int d4 = threadIdx.x & 31;
    if (node >= N_NODES) return;
    int s = rp[node], e = rp[node + 1];
    float ax = 0.f, ay = 0.f, az = 0.f, aw = 0.f;
    for (int i = s; i < e; i++) {
        float4 v = x4[csr[i] * 32 + d4];
        ax += v.x; ay += v.y; az += v.z; aw += v.w;
    }
    float inv = 1.0f / (float)max(e - s, 1);
    float4 o; o.x = ax * inv; o.y = ay * inv; o.z = az * inv; o.w = aw * inv;
    agg4[node * 32 + d4] = o;
}

// ---------------- fused dual-GEMM layer ----------------
// xout[n,j] = act( sum_k agg[n,k]*WlT[k,j] + sum_k x[n,k]*WrT[k,j] + b[j] ) (+ x[n,j] if residual)
// Block: 256 threads, tile 32 nodes x 128 outputs, 4x4 register accumulator per thread.
__global__ __launch_bounds__(256) void fused_layer(const float* __restrict__ agg,
                                                   const float* __restrict__ xin,
                                                   float* __restrict__ xout,
                                                   const float* __restrict__ WlT,
                                                   const float* __restrict__ WrT,
                                                   const float* __restrict__ bias,
                                                   int residual) {
    __shared__ __align__(16) float sA[DIM][36];  // agg transposed: [k][node], pad 36 (row=144B, 16B-mult)
    __shared__ __align__(16) float sX[DIM][36];  // x transposed
    int t = threadIdx.x;
    int node0 = blockIdx.x * 32;

    // stage 32 node-rows (transposed) into LDS
    int kq = t & 31, nr = t >> 5;  // kq: float4 column group, nr: node row (8 per pass)
    for (int p = 0; p < 4; p++) {
        int n = nr + p * 8;
        int gn = node0 + n;
        float4 a = make_float4(0.f, 0.f, 0.f, 0.f);
        float4 xv = make_float4(0.f, 0.f, 0.f, 0.f);
        if (gn < N_NODES) {
            a  = *(const float4*)&agg[gn * DIM + kq * 4];
            xv = *(const float4*)&xin[gn * DIM + kq * 4];
        }
        sA[kq * 4 + 0][n] = a.x;  sA[kq * 4 + 1][n] = a.y;
        sA[kq * 4 + 2][n] = a.z;  sA[kq * 4 + 3][n] = a.w;
        sX[kq * 4 + 0][n] = xv.x; sX[kq * 4 + 1][n] = xv.y;
        sX[kq * 4 + 2][n] = xv.z; sX[kq * 4 + 3][n] = xv.w;
    }
    __syncthreads();

    int tj = t & 31, tn = t >> 5;    // tj: j-quad (0..31), tn: node-quad (0..7)
    int j0 = tj * 4, n0 = tn * 4;

    float acc[4][4];
    {
        float4 b = *(const float4*)&bias[j0];
        for (int r = 0; r < 4; r++) {
            acc[r][0] = b.x; acc[r][1] = b.y; acc[r][2] = b.z; acc[r][3] = b.w;
        }
    }

#pragma unroll 4
    for (int k = 0; k < DIM; k++) {
        float4 wl4 = *(const float4*)&WlT[k * DIM + j0];
        float4 wr4 = *(const float4*)&WrT[k * DIM + j0];
        float4 av4 = *((const float4*)&sA[k][0] + tn);  // broadcast within half-wave
        float4 xv4 = *((const float4*)&sX[k][0] + tn);
        float wl[4] = {wl4.x, wl4.y, wl4.z, wl4.w};
        float wr[4] = {wr4.x, wr4.y, wr4.z, wr4.w};
        float av[4] = {av4.x, av4.y, av4.z, av4.w};
        float xv[4] = {xv4.x, xv4.y, xv4.z, xv4.w};
        for (int c = 0; c < 4; c++)
            for (int r = 0; r < 4; r++)
                acc[r][c] += av[r] * wl[c] + xv[r] * wr[c];
    }

    // epilogue: leaky-relu, optional residual (x read from LDS), store
    for (int r = 0; r < 4; r++) {
        int n = n0 + r;
        int gn = node0 + n;
        if (gn >= N_NODES) continue;
        float o[4];
        for (int c = 0; c < 4; c++) {
            float v = acc[r][c];
            v = (v >= 0.f) ? v : NEG_SLOPE * v;
            if (residual) v += sX[j0 + c][n];
            o[c] = v;
        }
        float4 ov = make_float4(o[0], o[1], o[2], o[3]);
        *(float4*)&xout[gn * DIM + j0] = ov;
    }
}

// ---------------- global mean pool ----------------
__global__ void pool_mean(const float* __restrict__ x, const int* __restrict__ gstart,
                          float* __restrict__ out) {
    int g = blockIdx.x, d = threadIdx.x;  // 64 blocks x 128 threads
    int s = gstart[g], e = gstart[g + 1];
    float s0 = 0.f, s1 = 0.f, s2 = 0.f, s3 = 0.f;
    int n = s;
    for (; n + 4 <= e; n += 4) {
        s0 += x[(n + 0) * DIM + d];
        s1 += x[(n + 1) * DIM + d];
        s2 += x[(n + 2) * DIM + d];
        s3 += x[(n + 3) * DIM + d];
    }
    for (; n < e; n++) s0 += x[n * DIM + d];
    float sum = (s0 + s1) + (s2 + s3);
    out[g * DIM + d] = sum / (float)max(e - s, 1);
}

// ---------------- launch ----------------

extern "C" void kernel_launch(void* const* d_in, const int* in_sizes, int n_in,
                              void* d_out, int out_size, void* d_ws, size_t ws_size,
                              hipStream_t stream) {
    const float* x     = (const float*)d_in[0];
    const int*   ei    = (const int*)d_in[1];
    const int*   batch = (const int*)d_in[2];
    const float* Wl    = (const float*)d_in[3];
    const float* bl    = (const float*)d_in[4];
    const float* Wr    = (const float*)d_in[5];
    float* out = (float*)d_out;

    const int* esrc = ei;            // edge_index[0]
    const int* edst = ei + N_EDGES;  // edge_index[1]

    // workspace layout (floats first, 16B-aligned throughout)
    float* xbuf = (float*)d_ws;                      // [N, D]
    float* agg  = xbuf + (size_t)N_NODES * DIM;      // [N, D]
    float* WlT  = agg  + (size_t)N_NODES * DIM;      // [L, D, D]
    float* WrT  = WlT  + (size_t)N_LAYERS * DIM * DIM;
    int* deg    = (int*)(WrT + (size_t)N_LAYERS * DIM * DIM);  // [N]
    int* fill   = deg + N_NODES;                     // [N]
    int* csr    = fill + N_NODES;                    // [E]
    int* rp     = csr + N_EDGES;                     // [N+1]
    int* gstart = rp + (N_NODES + 1);                // [G+1]

    // 1. zero deg+fill (adjacent)
    zero_ints<<<(2 * N_NODES + 255) / 256, 256, 0, stream>>>(deg, 2 * N_NODES);

    // 2. transpose weights
    transpose_w<<<dim3(4, 4, 8), dim3(32, 8), 0, stream>>>(Wl, Wr, WlT, WrT);

    // 3. CSR build
    count_deg<<<(N_EDGES + 255) / 256, 256, 0, stream>>>(edst, deg);
    scan_deg<<<1, 1024, 0, stream>>>(deg, rp);
    fill_csr<<<(N_EDGES + 255) / 256, 256, 0, stream>>>(esrc, edst, rp, fill, csr);

    // 4. graph segment starts
    graph_start<<<(N_NODES + 255) / 256, 256, 0, stream>>>(batch, gstart);

    // 5. layers
    int agg_blocks = (N_NODES + 7) / 8;
    int gemm_blocks = (N_NODES + 31) / 32;
    for (int l = 0; l < N_LAYERS; l++) {
        const float* xin = (l == 0) ? x : xbuf;
        agg_mean<<<agg_blocks, 256, 0, stream>>>((const float4*)xin, rp, csr, (float4*)agg);
        fused_layer<<<gemm_blocks, 256, 0, stream>>>(
            agg, xin, xbuf, WlT + (size_t)l * DIM * DIM, WrT + (size_t)l * DIM * DIM,
            bl + (size_t)l * DIM, (l >= 2) ? 1 : 0);
    }

    // 6. pool
    pool_mean<<<N_GRAPHS, DIM, 0, stream>>>(xbuf, gstart, out);
}

// Round 2
// 665.512 us; speedup vs baseline: 1.1461x; 1.1461x over previous
//
#include <hip/hip_runtime.h>

#define N_NODES 50000
#define N_EDGES 600000
#define DIM 128
#define N_LAYERS 4
#define N_GRAPHS 64
#define NEG_SLOPE 0.01f
#define NB_SCAN ((N_NODES + 255) / 256)  // 196 blocks

// ---------------- utility kernels ----------------

__global__ void zero_ints(int* p, int n) {
    int i = blockIdx.x * blockDim.x + threadIdx.x;
    if (i < n) p[i] = 0;
}

// transpose all 4 layers of Wl and Wr: WT[l][k][j] = W[l][j][k]
__global__ void transpose_w(const float* __restrict__ Wl, const float* __restrict__ Wr,
                            float* __restrict__ WlT, float* __restrict__ WrT) {
    __shared__ float tile[32][33];
    int z = blockIdx.z;  // 0..7 : 0-3 Wl layers, 4-7 Wr layers
    const float* src = (z < 4) ? (Wl + z * DIM * DIM) : (Wr + (z - 4) * DIM * DIM);
    float* dst = (z < 4) ? (WlT + z * DIM * DIM) : (WrT + (z - 4) * DIM * DIM);
    int k0 = blockIdx.x * 32, j0 = blockIdx.y * 32;
    int tx = threadIdx.x, ty = threadIdx.y;  // block (32,8)
    for (int r = 0; r < 32; r += 8)
        tile[ty + r][tx] = src[(j0 + ty + r) * DIM + k0 + tx];
    __syncthreads();
    for (int r = 0; r < 32; r += 8)
        dst[(k0 + ty + r) * DIM + j0 + tx] = tile[tx][ty + r];
}

__global__ void count_deg(const int* __restrict__ dst, int* deg) {
    int e = blockIdx.x * blockDim.x + threadIdx.x;
    if (e < N_EDGES) atomicAdd(&deg[dst[e]], 1);
}

// ---------------- 3-pass exclusive scan of deg -> rp ----------------
__global__ void scan_pass1(const int* __restrict__ deg, int* __restrict__ bsum) {
    int i = blockIdx.x * 256 + threadIdx.x;
    int v = (i < N_NODES) ? deg[i] : 0;
    for (int off = 32; off > 0; off >>= 1) v += __shfl_down(v, off, 64);
    __shared__ int ws[4];
    int lane = threadIdx.x & 63, w = threadIdx.x >> 6;
    if (lane == 0) ws[w] = v;
    __syncthreads();
    if (threadIdx.x == 0) bsum[blockIdx.x] = ws[0] + ws[1] + ws[2] + ws[3];
}

__global__ void scan_pass2(int* __restrict__ bsum) {
    __shared__ int sm[256];
    int t = threadIdx.x;
    int v = (t < NB_SCAN) ? bsum[t] : 0;
    sm[t] = v;
    __syncthreads();
    for (int off = 1; off < 256; off <<= 1) {
        int u = (t >= off) ? sm[t - off] : 0;
        __syncthreads();
        sm[t] += u;
        __syncthreads();
    }
    if (t < NB_SCAN) bsum[t] = sm[t] - v;  // exclusive block offset
}

__global__ void scan_pass3(const int* __restrict__ deg, const int* __restrict__ bsum,
                           int* __restrict__ rp) {
    int i = blockIdx.x * 256 + threadIdx.x;
    int v = (i < N_NODES) ? deg[i] : 0;
    int lane = threadIdx.x & 63, w = threadIdx.x >> 6;
    int s = v;
    for (int off = 1; off < 64; off <<= 1) {
        int t = __shfl_up(s, off, 64);
        if (lane >= off) s += t;
    }
    __shared__ int ws[4];
    if (lane == 63) ws[w] = s;
    __syncthreads();
    int wo = 0;
    for (int k = 0; k < 4; k++) wo += (k < w) ? ws[k] : 0;
    int incl = s + wo + bsum[blockIdx.x];
    if (i < N_NODES) rp[i + 1] = incl;
    if (i == 0) rp[0] = 0;
}

__global__ void fill_csr(const int* __restrict__ src, const int* __restrict__ dst,
                         const int* __restrict__ rp, int* __restrict__ fill,
                         int* __restrict__ csr) {
    int e = blockIdx.x * blockDim.x + threadIdx.x;
    if (e >= N_EDGES) return;
    int d = dst[e];
    int pos = atomicAdd(&fill[d], 1);
    csr[rp[d] + pos] = src[e];
}

// graph segment starts from sorted batch vector
__global__ void graph_start(const int* __restrict__ batch, int* __restrict__ gstart) {
    int i = blockIdx.x * blockDim.x + threadIdx.x;
    if (i >= N_NODES) return;
    int b = batch[i];
    if (i == 0) {
        for (int g = 0; g <= b; g++) gstart[g] = 0;
    } else {
        int p = batch[i - 1];
        for (int g = p + 1; g <= b; g++) gstart[g] = i;
    }
    if (i == N_NODES - 1) {
        for (int g = b + 1; g <= N_GRAPHS; g++) gstart[g] = N_NODES;
    }
}

// ---------------- aggregation: mean over in-neighbors via CSR gather ----------------
// 8 nodes per 256-thread block; 32 lanes per node, float4 per lane.
__global__ __launch_bounds__(256) void agg_mean(const float4* __restrict__ x4,
                                                const int* __restrict__ rp,
                                                const int* __restrict__ csr,
                                                float4* __restrict__ agg4) {
    int node = blockIdx.x * 8 + (threadIdx.x >> 5);
    int d4 = threadIdx.x & 31;
    if (node >= N_NODES) return;
    int s = rp[node], e = rp[node + 1];
    float ax = 0.f, ay = 0.f, az = 0.f, aw = 0.f;
    int i = s;
    for (; i + 2 <= e; i += 2) {
        int n0 = csr[i], n1 = csr[i + 1];
        float4 v0 = x4[n0 * 32 + d4];
        float4 v1 = x4[n1 * 32 + d4];
        ax += v0.x + v1.x; ay += v0.y + v1.y;
        az += v0.z + v1.z; aw += v0.w + v1.w;
    }
    if (i < e) {
        float4 v = x4[csr[i] * 32 + d4];
        ax += v.x; ay += v.y; az += v.z; aw += v.w;
    }
    float inv = 1.0f / (float)max(e - s, 1);
    float4 o; o.x = ax * inv; o.y = ay * inv; o.z = az * inv; o.w = aw * inv;
    agg4[node * 32 + d4] = o;
}

// ---------------- fused dual-GEMM layer ----------------
// xout[n,j] = act( sum_k agg[n,k]*WlT[k,j] + sum_k x[n,k]*WrT[k,j] + b[j] ) (+ x[n,j] if residual)
__global__ __launch_bounds__(256) void fused_layer(const float* __restrict__ agg,
                                                   const float* __restrict__ xin,
                                                   float* __restrict__ xout,
                                                   const float* __restrict__ WlT,
                                                   const float* __restrict__ WrT,
                                                   const float* __restrict__ bias,
                                                   int residual) {
    __shared__ __align__(16) float sA[DIM][36];  // agg transposed: [k][node]
    __shared__ __align__(16) float sX[DIM][36];  // x transposed
    int t = threadIdx.x;
    int node0 = blockIdx.x * 32;

    int kq = t & 31, nr = t >> 5;
    for (int p = 0; p < 4; p++) {
        int n = nr + p * 8;
        int gn = node0 + n;
        float4 a = make_float4(0.f, 0.f, 0.f, 0.f);
        float4 xv = make_float4(0.f, 0.f, 0.f, 0.f);
        if (gn < N_NODES) {
            a  = *(const float4*)&agg[gn * DIM + kq * 4];
            xv = *(const float4*)&xin[gn * DIM + kq * 4];
        }
        sA[kq * 4 + 0][n] = a.x;  sA[kq * 4 + 1][n] = a.y;
        sA[kq * 4 + 2][n] = a.z;  sA[kq * 4 + 3][n] = a.w;
        sX[kq * 4 + 0][n] = xv.x; sX[kq * 4 + 1][n] = xv.y;
        sX[kq * 4 + 2][n] = xv.z; sX[kq * 4 + 3][n] = xv.w;
    }
    __syncthreads();

    int tj = t & 31, tn = t >> 5;
    int j0 = tj * 4, n0 = tn * 4;

    float acc[4][4];
    {
        float4 b = *(const float4*)&bias[j0];
        for (int r = 0; r < 4; r++) {
            acc[r][0] = b.x; acc[r][1] = b.y; acc[r][2] = b.z; acc[r][3] = b.w;
        }
    }

#pragma unroll 4
    for (int k = 0; k < DIM; k++) {
        float4 wl4 = *(const float4*)&WlT[k * DIM + j0];
        float4 wr4 = *(const float4*)&WrT[k * DIM + j0];
        float4 av4 = *((const float4*)&sA[k][0] + tn);
        float4 xv4 = *((const float4*)&sX[k][0] + tn);
        float wl[4] = {wl4.x, wl4.y, wl4.z, wl4.w};
        float wr[4] = {wr4.x, wr4.y, wr4.z, wr4.w};
        float av[4] = {av4.x, av4.y, av4.z, av4.w};
        float xv[4] = {xv4.x, xv4.y, xv4.z, xv4.w};
        for (int c = 0; c < 4; c++)
            for (int r = 0; r < 4; r++)
                acc[r][c] += av[r] * wl[c] + xv[r] * wr[c];
    }

    for (int r = 0; r < 4; r++) {
        int n = n0 + r;
        int gn = node0 + n;
        if (gn >= N_NODES) continue;
        float o[4];
        for (int c = 0; c < 4; c++) {
            float v = acc[r][c];
            v = (v >= 0.f) ? v : NEG_SLOPE * v;
            if (residual) v += sX[j0 + c][n];
            o[c] = v;
        }
        float4 ov = make_float4(o[0], o[1], o[2], o[3]);
        *(float4*)&xout[gn * DIM + j0] = ov;
    }
}

// ---------------- global mean pool ----------------
__global__ void pool_mean(const float* __restrict__ x, const int* __restrict__ gstart,
                          float* __restrict__ out) {
    int g = blockIdx.x, d = threadIdx.x;  // 64 blocks x 128 threads
    int s = gstart[g], e = gstart[g + 1];
    float s0 = 0.f, s1 = 0.f, s2 = 0.f, s3 = 0.f;
    int n = s;
    for (; n + 4 <= e; n += 4) {
        s0 += x[(n + 0) * DIM + d];
        s1 += x[(n + 1) * DIM + d];
        s2 += x[(n + 2) * DIM + d];
        s3 += x[(n + 3) * DIM + d];
    }
    for (; n < e; n++) s0 += x[n * DIM + d];
    float sum = (s0 + s1) + (s2 + s3);
    out[g * DIM + d] = sum / (float)max(e - s, 1);
}

// ---------------- launch ----------------

extern "C" void kernel_launch(void* const* d_in, const int* in_sizes, int n_in,
                              void* d_out, int out_size, void* d_ws, size_t ws_size,
                              hipStream_t stream) {
    const float* x     = (const float*)d_in[0];
    const int*   ei    = (const int*)d_in[1];
    const int*   batch = (const int*)d_in[2];
    const float* Wl    = (const float*)d_in[3];
    const float* bl    = (const float*)d_in[4];
    const float* Wr    = (const float*)d_in[5];
    float* out = (float*)d_out;

    const int* esrc = ei;            // edge_index[0]
    const int* edst = ei + N_EDGES;  // edge_index[1]

    // workspace layout
    float* xbuf = (float*)d_ws;                      // [N, D]
    float* agg  = xbuf + (size_t)N_NODES * DIM;      // [N, D]
    float* WlT  = agg  + (size_t)N_NODES * DIM;      // [L, D, D]
    float* WrT  = WlT  + (size_t)N_LAYERS * DIM * DIM;
    int* deg    = (int*)(WrT + (size_t)N_LAYERS * DIM * DIM);  // [N]
    int* fill   = deg + N_NODES;                     // [N]
    int* csr    = fill + N_NODES;                    // [E]
    int* rp     = csr + N_EDGES;                     // [N+1]
    int* gstart = rp + (N_NODES + 1);                // [G+1]
    int* bsum   = gstart + (N_GRAPHS + 1);           // [NB_SCAN]

    zero_ints<<<(2 * N_NODES + 255) / 256, 256, 0, stream>>>(deg, 2 * N_NODES);
    transpose_w<<<dim3(4, 4, 8), dim3(32, 8), 0, stream>>>(Wl, Wr, WlT, WrT);
    count_deg<<<(N_EDGES + 255) / 256, 256, 0, stream>>>(edst, deg);

    scan_pass1<<<NB_SCAN, 256, 0, stream>>>(deg, bsum);
    scan_pass2<<<1, 256, 0, stream>>>(bsum);
    scan_pass3<<<NB_SCAN, 256, 0, stream>>>(deg, bsum, rp);

    fill_csr<<<(N_EDGES + 255) / 256, 256, 0, stream>>>(esrc, edst, rp, fill, csr);
    graph_start<<<(N_NODES + 255) / 256, 256, 0, stream>>>(batch, gstart);

    int agg_blocks = (N_NODES + 7) / 8;
    int gemm_blocks = (N_NODES + 31) / 32;
    for (int l = 0; l < N_LAYERS; l++) {
        const float* xin = (l == 0) ? x : xbuf;
        agg_mean<<<agg_blocks, 256, 0, stream>>>((const float4*)xin, rp, csr, (float4*)agg);
        fused_layer<<<gemm_blocks, 256, 0, stream>>>(
            agg, xin, xbuf, WlT + (size_t)l * DIM * DIM, WrT + (size_t)l * DIM * DIM,
            bl + (size_t)l * DIM, (l >= 2) ? 1 : 0);
    }

    pool_mean<<<N_GRAPHS, DIM, 0, stream>>>(xbuf, gstart, out);
}

// Round 3
// 410.918 us; speedup vs baseline: 1.8562x; 1.6196x over previous
//
#include <hip/hip_runtime.h>

#define N_NODES 50000
#define N_EDGES 600000
#define DIM 128
#define N_LAYERS 4
#define N_GRAPHS 64
#define NEG_SLOPE 0.01f
#define NB_SCAN ((N_NODES + 255) / 256)  // 196 blocks
#define RS 264  // LDS row stride in bf16 elems: 256 data + 8 pad (16B)

typedef __attribute__((ext_vector_type(8))) short short8;
typedef __attribute__((ext_vector_type(16))) float floatx16;

__device__ __forceinline__ unsigned short f2bf(float f) {
    union { float f; unsigned u; } c; c.f = f;
    unsigned u = c.u;
    unsigned r = (u + 0x7FFFu + ((u >> 16) & 1u)) >> 16;
    return (unsigned short)r;
}
__device__ __forceinline__ float bfraw2f(unsigned short b) {
    union { unsigned u; float f; } c; c.u = ((unsigned)b) << 16;
    return c.f;
}
__device__ __forceinline__ float bflo(unsigned u) {
    union { unsigned u; float f; } c; c.u = u << 16; return c.f;
}
__device__ __forceinline__ float bfhi(unsigned u) {
    union { unsigned u; float f; } c; c.u = u & 0xFFFF0000u; return c.f;
}

// ---------------- utility kernels ----------------

__global__ void zero_ints(int* p, int n) {
    int i = blockIdx.x * blockDim.x + threadIdx.x;
    if (i < n) p[i] = 0;
}

// convert fp32 x -> bf16 (8 elems per thread)
__global__ void convert_x(const float4* __restrict__ x, uint4* __restrict__ xb) {
    int i = blockIdx.x * blockDim.x + threadIdx.x;  // chunk of 8 floats
    if (i >= N_NODES * DIM / 8) return;
    float4 a = x[i * 2], b = x[i * 2 + 1];
    uint4 o;
    o.x = ((unsigned)f2bf(a.y) << 16) | f2bf(a.x);
    o.y = ((unsigned)f2bf(a.w) << 16) | f2bf(a.z);
    o.z = ((unsigned)f2bf(b.y) << 16) | f2bf(b.x);
    o.w = ((unsigned)f2bf(b.w) << 16) | f2bf(b.z);
    xb[i] = o;
}

// pack weights into MFMA B-fragment order (bf16), for v_mfma_f32_32x32x16_bf16.
// B[k][n] = W[n][k]. Fragment (layer, m, s, t): lane l holds B[s*16+(l>>5)*8+j][t*32+(l&31)], j=0..7.
// ushort offset = ((((layer*2+m)*8 + s)*4 + t)*64 + l)*8 + j
__global__ void pack_w(const float* __restrict__ Wl, const float* __restrict__ Wr,
                       ushort* __restrict__ wpk) {
    int s = blockIdx.x >> 2, t = blockIdx.x & 3;
    int m = blockIdx.y, layer = blockIdx.z;
    int l = threadIdx.x;  // 64 lanes
    const float* W = ((m == 0) ? Wl : Wr) + (size_t)layer * DIM * DIM;
    int n = t * 32 + (l & 31);
    int kb = s * 16 + (l >> 5) * 8;
    size_t off = ((((size_t)(layer * 2 + m) * 8 + s) * 4 + t) * 64 + l) * 8;
    for (int j = 0; j < 8; j++)
        wpk[off + j] = f2bf(W[n * DIM + kb + j]);
}

__global__ void count_deg(const int* __restrict__ dst, int* deg) {
    int e = blockIdx.x * blockDim.x + threadIdx.x;
    if (e < N_EDGES) atomicAdd(&deg[dst[e]], 1);
}

// ---------------- 3-pass exclusive scan of deg -> rp ----------------
__global__ void scan_pass1(const int* __restrict__ deg, int* __restrict__ bsum) {
    int i = blockIdx.x * 256 + threadIdx.x;
    int v = (i < N_NODES) ? deg[i] : 0;
    for (int off = 32; off > 0; off >>= 1) v += __shfl_down(v, off, 64);
    __shared__ int ws[4];
    int lane = threadIdx.x & 63, w = threadIdx.x >> 6;
    if (lane == 0) ws[w] = v;
    __syncthreads();
    if (threadIdx.x == 0) bsum[blockIdx.x] = ws[0] + ws[1] + ws[2] + ws[3];
}

__global__ void scan_pass2(int* __restrict__ bsum) {
    __shared__ int sm[256];
    int t = threadIdx.x;
    int v = (t < NB_SCAN) ? bsum[t] : 0;
    sm[t] = v;
    __syncthreads();
    for (int off = 1; off < 256; off <<= 1) {
        int u = (t >= off) ? sm[t - off] : 0;
        __syncthreads();
        sm[t] += u;
        __syncthreads();
    }
    if (t < NB_SCAN) bsum[t] = sm[t] - v;
}

__global__ void scan_pass3(const int* __restrict__ deg, const int* __restrict__ bsum,
                           int* __restrict__ rp) {
    int i = blockIdx.x * 256 + threadIdx.x;
    int v = (i < N_NODES) ? deg[i] : 0;
    int lane = threadIdx.x & 63, w = threadIdx.x >> 6;
    int s = v;
    for (int off = 1; off < 64; off <<= 1) {
        int t = __shfl_up(s, off, 64);
        if (lane >= off) s += t;
    }
    __shared__ int ws[4];
    if (lane == 63) ws[w] = s;
    __syncthreads();
    int wo = 0;
    for (int k = 0; k < 4; k++) wo += (k < w) ? ws[k] : 0;
    int incl = s + wo + bsum[blockIdx.x];
    if (i < N_NODES) rp[i + 1] = incl;
    if (i == 0) rp[0] = 0;
}

__global__ void fill_csr(const int* __restrict__ src, const int* __restrict__ dst,
                         const int* __restrict__ rp, int* __restrict__ fill,
                         int* __restrict__ csr) {
    int e = blockIdx.x * blockDim.x + threadIdx.x;
    if (e >= N_EDGES) return;
    int d = dst[e];
    int pos = atomicAdd(&fill[d], 1);
    csr[rp[d] + pos] = src[e];
}

__global__ void graph_start(const int* __restrict__ batch, int* __restrict__ gstart) {
    int i = blockIdx.x * blockDim.x + threadIdx.x;
    if (i >= N_NODES) return;
    int b = batch[i];
    if (i == 0) {
        for (int g = 0; g <= b; g++) gstart[g] = 0;
    } else {
        int p = batch[i - 1];
        for (int g = p + 1; g <= b; g++) gstart[g] = i;
    }
    if (i == N_NODES - 1) {
        for (int g = b + 1; g <= N_GRAPHS; g++) gstart[g] = N_NODES;
    }
}

// ---------------- aggregation: mean over in-neighbors, bf16 gather ----------------
// 16 nodes per 256-thread block; 16 lanes per node, 8 bf16 dims (16B) per lane.
__global__ __launch_bounds__(256) void agg_mean_bf16(const uint4* __restrict__ xb4,
                                                     const int* __restrict__ rp,
                                                     const int* __restrict__ csr,
                                                     uint4* __restrict__ agg4) {
    int node = blockIdx.x * 16 + (threadIdx.x >> 4);
    int ln = threadIdx.x & 15;
    if (node >= N_NODES) return;
    int s = rp[node], e = rp[node + 1];
    float a0 = 0.f, a1 = 0.f, a2 = 0.f, a3 = 0.f, a4 = 0.f, a5 = 0.f, a6 = 0.f, a7 = 0.f;
    int i = s;
    for (; i + 2 <= e; i += 2) {
        int n0 = csr[i], n1 = csr[i + 1];
        uint4 v0 = xb4[n0 * 16 + ln];
        uint4 v1 = xb4[n1 * 16 + ln];
        a0 += bflo(v0.x) + bflo(v1.x); a1 += bfhi(v0.x) + bfhi(v1.x);
        a2 += bflo(v0.y) + bflo(v1.y); a3 += bfhi(v0.y) + bfhi(v1.y);
        a4 += bflo(v0.z) + bflo(v1.z); a5 += bfhi(v0.z) + bfhi(v1.z);
        a6 += bflo(v0.w) + bflo(v1.w); a7 += bfhi(v0.w) + bfhi(v1.w);
    }
    if (i < e) {
        uint4 v = xb4[csr[i] * 16 + ln];
        a0 += bflo(v.x); a1 += bfhi(v.x);
        a2 += bflo(v.y); a3 += bfhi(v.y);
        a4 += bflo(v.z); a5 += bfhi(v.z);
        a6 += bflo(v.w); a7 += bfhi(v.w);
    }
    float inv = 1.0f / (float)max(e - s, 1);
    uint4 o;
    o.x = ((unsigned)f2bf(a1 * inv) << 16) | f2bf(a0 * inv);
    o.y = ((unsigned)f2bf(a3 * inv) << 16) | f2bf(a2 * inv);
    o.z = ((unsigned)f2bf(a5 * inv) << 16) | f2bf(a4 * inv);
    o.w = ((unsigned)f2bf(a7 * inv) << 16) | f2bf(a6 * inv);
    agg4[node * 16 + ln] = o;
}

// ---------------- fused dual-GEMM layer, MFMA bf16 ----------------
// out[n,j] = leaky( [agg|x] @ [Wl;Wr]^T + b ) (+x). Block: 128 nodes x 128 out, 4 waves.
__global__ __launch_bounds__(256) void fused_layer_mfma(const ushort* __restrict__ agg,
                                                        const ushort* __restrict__ xin,
                                                        ushort* __restrict__ xout,
                                                        const ushort* __restrict__ wpk,
                                                        const float* __restrict__ bias,
                                                        int residual) {
    __shared__ ushort sA[128 * RS];  // row r: [agg(128) | x(128) | pad(8)]
    int t = threadIdx.x;
    int node0 = blockIdx.x * 128;

    // stage: 4096 16B chunks; chunk i -> row r=i>>5, c=i&31 (c<16: agg, else x)
    const uint4* aggv = (const uint4*)(agg + (size_t)node0 * DIM);
    const uint4* xv   = (const uint4*)(xin + (size_t)node0 * DIM);
    for (int i = t; i < 128 * 32; i += 256) {
        int r = i >> 5, c = i & 31;
        uint4 val = make_uint4(0u, 0u, 0u, 0u);
        if (node0 + r < N_NODES)
            val = (c < 16) ? aggv[r * 16 + c] : xv[r * 16 + (c - 16)];
        *(uint4*)&sA[r * RS + c * 8] = val;
    }
    __syncthreads();

    int wv = t >> 6, l = t & 63;
    int m0 = wv * 32;
    const ushort* arow = &sA[(m0 + (l & 31)) * RS];
    int khalf = (l >> 5) * 8;

    floatx16 acc0 = {0.f}, acc1 = {0.f}, acc2 = {0.f}, acc3 = {0.f};
    for (int ii = 0; ii < 16; ii++) acc0[ii] = acc1[ii] = acc2[ii] = acc3[ii] = 0.f;

    const ushort* wl8 = wpk + (size_t)l * 8;  // lane's 16B chunk within a fragment
#pragma unroll
    for (int s2 = 0; s2 < 16; s2++) {
        int m = s2 >> 3, s = s2 & 7;
        short8 a = *(const short8*)(arow + m * 128 + s * 16 + khalf);
        size_t fb = (size_t)((m * 8 + s) * 4) * 512;  // fragment = 64 lanes * 8 elems = 512
        short8 b0 = *(const short8*)(wl8 + fb);
        short8 b1 = *(const short8*)(wl8 + fb + 512);
        short8 b2 = *(const short8*)(wl8 + fb + 1024);
        short8 b3 = *(const short8*)(wl8 + fb + 1536);
        acc0 = __builtin_amdgcn_mfma_f32_32x32x16_bf16(a, b0, acc0, 0, 0, 0);
        acc1 = __builtin_amdgcn_mfma_f32_32x32x16_bf16(a, b1, acc1, 0, 0, 0);
        acc2 = __builtin_amdgcn_mfma_f32_32x32x16_bf16(a, b2, acc2, 0, 0, 0);
        acc3 = __builtin_amdgcn_mfma_f32_32x32x16_bf16(a, b3, acc3, 0, 0, 0);
    }

    // epilogue: C/D layout col=lane&31, row=(reg&3)+8*(reg>>2)+4*(lane>>5)
    int col = l & 31;
    int rbase = 4 * (l >> 5);
    floatx16 accs[4] = {acc0, acc1, acc2, acc3};
    for (int t4 = 0; t4 < 4; t4++) {
        int n = t4 * 32 + col;
        float bv = bias[n];
#pragma unroll
        for (int r = 0; r < 16; r++) {
            int row = (r & 3) + 8 * (r >> 2) + rbase;
            int gm = m0 + row;
            int gn = node0 + gm;
            if (gn >= N_NODES) continue;
            float v = accs[t4][r] + bv;
            v = (v >= 0.f) ? v : NEG_SLOPE * v;
            if (residual) v += bfraw2f(sA[gm * RS + 128 + n]);
            xout[(size_t)gn * DIM + n] = f2bf(v);
        }
    }
}

// ---------------- global mean pool (bf16 in, fp32 out) ----------------
__global__ void pool_mean(const ushort* __restrict__ xb, const int* __restrict__ gstart,
                          float* __restrict__ out) {
    int g = blockIdx.x, d = threadIdx.x;  // 64 blocks x 128 threads
    int s = gstart[g], e = gstart[g + 1];
    float s0 = 0.f, s1 = 0.f, s2 = 0.f, s3 = 0.f;
    int n = s;
    for (; n + 4 <= e; n += 4) {
        s0 += bfraw2f(xb[(size_t)(n + 0) * DIM + d]);
        s1 += bfraw2f(xb[(size_t)(n + 1) * DIM + d]);
        s2 += bfraw2f(xb[(size_t)(n + 2) * DIM + d]);
        s3 += bfraw2f(xb[(size_t)(n + 3) * DIM + d]);
    }
    for (; n < e; n++) s0 += bfraw2f(xb[(size_t)n * DIM + d]);
    float sum = (s0 + s1) + (s2 + s3);
    out[g * DIM + d] = sum / (float)max(e - s, 1);
}

// ---------------- launch ----------------

extern "C" void kernel_launch(void* const* d_in, const int* in_sizes, int n_in,
                              void* d_out, int out_size, void* d_ws, size_t ws_size,
                              hipStream_t stream) {
    const float* x     = (const float*)d_in[0];
    const int*   ei    = (const int*)d_in[1];
    const int*   batch = (const int*)d_in[2];
    const float* Wl    = (const float*)d_in[3];
    const float* bl    = (const float*)d_in[4];
    const float* Wr    = (const float*)d_in[5];
    float* out = (float*)d_out;

    const int* esrc = ei;
    const int* edst = ei + N_EDGES;

    // workspace layout
    ushort* xb0  = (ushort*)d_ws;                         // [N,128] bf16
    ushort* xbuf = xb0 + (size_t)N_NODES * DIM;           // [N,128] bf16
    ushort* agg  = xbuf + (size_t)N_NODES * DIM;          // [N,128] bf16
    ushort* wpk  = agg + (size_t)N_NODES * DIM;           // [4][2][128*128] bf16
    int* deg    = (int*)(wpk + (size_t)N_LAYERS * 2 * DIM * DIM);
    int* fill   = deg + N_NODES;
    int* csr    = fill + N_NODES;
    int* rp     = csr + N_EDGES;
    int* gstart = rp + (N_NODES + 1);
    int* bsum   = gstart + (N_GRAPHS + 1);

    zero_ints<<<(2 * N_NODES + 255) / 256, 256, 0, stream>>>(deg, 2 * N_NODES);
    convert_x<<<(N_NODES * DIM / 8 + 255) / 256, 256, 0, stream>>>((const float4*)x, (uint4*)xb0);
    pack_w<<<dim3(32, 2, 4), 64, 0, stream>>>(Wl, Wr, wpk);
    count_deg<<<(N_EDGES + 255) / 256, 256, 0, stream>>>(edst, deg);

    scan_pass1<<<NB_SCAN, 256, 0, stream>>>(deg, bsum);
    scan_pass2<<<1, 256, 0, stream>>>(bsum);
    scan_pass3<<<NB_SCAN, 256, 0, stream>>>(deg, bsum, rp);

    fill_csr<<<(N_EDGES + 255) / 256, 256, 0, stream>>>(esrc, edst, rp, fill, csr);
    graph_start<<<(N_NODES + 255) / 256, 256, 0, stream>>>(batch, gstart);

    int agg_blocks = (N_NODES + 15) / 16;
    int gemm_blocks = (N_NODES + 127) / 128;
    for (int l = 0; l < N_LAYERS; l++) {
        const ushort* xin = (l == 0) ? xb0 : xbuf;
        agg_mean_bf16<<<agg_blocks, 256, 0, stream>>>((const uint4*)xin, rp, csr, (uint4*)agg);
        fused_layer_mfma<<<gemm_blocks, 256, 0, stream>>>(
            agg, xin, xbuf, wpk + (size_t)l * 2 * DIM * DIM,
            bl + (size_t)l * DIM, (l >= 2) ? 1 : 0);
    }

    pool_mean<<<N_GRAPHS, DIM, 0, stream>>>(xbuf, gstart, out);
}

// Round 4
// 378.498 us; speedup vs baseline: 2.0152x; 1.0857x over previous
//
#include <hip/hip_runtime.h>

#define N_NODES 50000
#define N_EDGES 600000
#define DIM 128
#define N_LAYERS 4
#define N_GRAPHS 64
#define NEG_SLOPE 0.01f
#define NB_SCAN ((N_NODES + 255) / 256)  // 196 blocks
#define RS 264  // LDS row stride in bf16 elems: 256 data + 8 pad (16B)

typedef __attribute__((ext_vector_type(8))) short short8;
typedef __attribute__((ext_vector_type(16))) float floatx16;

__device__ __forceinline__ unsigned short f2bf(float f) {
    union { float f; unsigned u; } c; c.f = f;
    unsigned u = c.u;
    unsigned r = (u + 0x7FFFu + ((u >> 16) & 1u)) >> 16;
    return (unsigned short)r;
}
__device__ __forceinline__ float bfraw2f(unsigned short b) {
    union { unsigned u; float f; } c; c.u = ((unsigned)b) << 16;
    return c.f;
}
__device__ __forceinline__ float bflo(unsigned u) {
    union { unsigned u; float f; } c; c.u = u << 16; return c.f;
}
__device__ __forceinline__ float bfhi(unsigned u) {
    union { unsigned u; float f; } c; c.u = u & 0xFFFF0000u; return c.f;
}

// ---------------- utility kernels ----------------

__global__ void zero_ints(int* p, int n) {
    int i = blockIdx.x * blockDim.x + threadIdx.x;
    if (i < n) p[i] = 0;
}

// convert fp32 x -> bf16 (8 elems per thread)
__global__ void convert_x(const float4* __restrict__ x, uint4* __restrict__ xb) {
    int i = blockIdx.x * blockDim.x + threadIdx.x;  // chunk of 8 floats
    if (i >= N_NODES * DIM / 8) return;
    float4 a = x[i * 2], b = x[i * 2 + 1];
    uint4 o;
    o.x = ((unsigned)f2bf(a.y) << 16) | f2bf(a.x);
    o.y = ((unsigned)f2bf(a.w) << 16) | f2bf(a.z);
    o.z = ((unsigned)f2bf(b.y) << 16) | f2bf(b.x);
    o.w = ((unsigned)f2bf(b.w) << 16) | f2bf(b.z);
    xb[i] = o;
}

// pack weights into MFMA B-fragment order (bf16), for v_mfma_f32_32x32x16_bf16.
// B[k][n] = W[n][k]. Fragment (layer, m, s, t): lane l holds B[s*16+(l>>5)*8+j][t*32+(l&31)], j=0..7.
__global__ void pack_w(const float* __restrict__ Wl, const float* __restrict__ Wr,
                       ushort* __restrict__ wpk) {
    int s = blockIdx.x >> 2, t = blockIdx.x & 3;
    int m = blockIdx.y, layer = blockIdx.z;
    int l = threadIdx.x;  // 64 lanes
    const float* W = ((m == 0) ? Wl : Wr) + (size_t)layer * DIM * DIM;
    int n = t * 32 + (l & 31);
    int kb = s * 16 + (l >> 5) * 8;
    size_t off = ((((size_t)(layer * 2 + m) * 8 + s) * 4 + t) * 64 + l) * 8;
    for (int j = 0; j < 8; j++)
        wpk[off + j] = f2bf(W[n * DIM + kb + j]);
}

__global__ void count_deg(const int* __restrict__ dst, int* deg) {
    int e = blockIdx.x * blockDim.x + threadIdx.x;
    if (e < N_EDGES) atomicAdd(&deg[dst[e]], 1);
}

// ---------------- 3-pass exclusive scan of deg -> rp ----------------
__global__ void scan_pass1(const int* __restrict__ deg, int* __restrict__ bsum) {
    int i = blockIdx.x * 256 + threadIdx.x;
    int v = (i < N_NODES) ? deg[i] : 0;
    for (int off = 32; off > 0; off >>= 1) v += __shfl_down(v, off, 64);
    __shared__ int ws[4];
    int lane = threadIdx.x & 63, w = threadIdx.x >> 6;
    if (lane == 0) ws[w] = v;
    __syncthreads();
    if (threadIdx.x == 0) bsum[blockIdx.x] = ws[0] + ws[1] + ws[2] + ws[3];
}

__global__ void scan_pass2(int* __restrict__ bsum) {
    __shared__ int sm[256];
    int t = threadIdx.x;
    int v = (t < NB_SCAN) ? bsum[t] : 0;
    sm[t] = v;
    __syncthreads();
    for (int off = 1; off < 256; off <<= 1) {
        int u = (t >= off) ? sm[t - off] : 0;
        __syncthreads();
        sm[t] += u;
        __syncthreads();
    }
    if (t < NB_SCAN) bsum[t] = sm[t] - v;
}

__global__ void scan_pass3(const int* __restrict__ deg, const int* __restrict__ bsum,
                           int* __restrict__ rp) {
    int i = blockIdx.x * 256 + threadIdx.x;
    int v = (i < N_NODES) ? deg[i] : 0;
    int lane = threadIdx.x & 63, w = threadIdx.x >> 6;
    int s = v;
    for (int off = 1; off < 64; off <<= 1) {
        int t = __shfl_up(s, off, 64);
        if (lane >= off) s += t;
    }
    __shared__ int ws[4];
    if (lane == 63) ws[w] = s;
    __syncthreads();
    int wo = 0;
    for (int k = 0; k < 4; k++) wo += (k < w) ? ws[k] : 0;
    int incl = s + wo + bsum[blockIdx.x];
    if (i < N_NODES) rp[i + 1] = incl;
    if (i == 0) rp[0] = 0;
}

__global__ void fill_csr(const int* __restrict__ src, const int* __restrict__ dst,
                         const int* __restrict__ rp, int* __restrict__ fill,
                         int* __restrict__ csr) {
    int e = blockIdx.x * blockDim.x + threadIdx.x;
    if (e >= N_EDGES) return;
    int d = dst[e];
    int pos = atomicAdd(&fill[d], 1);
    csr[rp[d] + pos] = src[e];
}

__global__ void graph_start(const int* __restrict__ batch, int* __restrict__ gstart) {
    int i = blockIdx.x * blockDim.x + threadIdx.x;
    if (i >= N_NODES) return;
    int b = batch[i];
    if (i == 0) {
        for (int g = 0; g <= b; g++) gstart[g] = 0;
    } else {
        int p = batch[i - 1];
        for (int g = p + 1; g <= b; g++) gstart[g] = i;
    }
    if (i == N_NODES - 1) {
        for (int g = b + 1; g <= N_GRAPHS; g++) gstart[g] = N_NODES;
    }
}

// ---------------- aggregation: mean over in-neighbors, bf16 gather ----------------
// 16 nodes per 256-thread block; 16 lanes per node, 8 bf16 dims (16B) per lane.
__global__ __launch_bounds__(256) void agg_mean_bf16(const uint4* __restrict__ xb4,
                                                     const int* __restrict__ rp,
                                                     const int* __restrict__ csr,
                                                     uint4* __restrict__ agg4) {
    int node = blockIdx.x * 16 + (threadIdx.x >> 4);
    int ln = threadIdx.x & 15;
    if (node >= N_NODES) return;
    int s = rp[node], e = rp[node + 1];
    float a0 = 0.f, a1 = 0.f, a2 = 0.f, a3 = 0.f, a4 = 0.f, a5 = 0.f, a6 = 0.f, a7 = 0.f;
    int i = s;
    for (; i + 2 <= e; i += 2) {
        int n0 = csr[i], n1 = csr[i + 1];
        uint4 v0 = xb4[n0 * 16 + ln];
        uint4 v1 = xb4[n1 * 16 + ln];
        a0 += bflo(v0.x) + bflo(v1.x); a1 += bfhi(v0.x) + bfhi(v1.x);
        a2 += bflo(v0.y) + bflo(v1.y); a3 += bfhi(v0.y) + bfhi(v1.y);
        a4 += bflo(v0.z) + bflo(v1.z); a5 += bfhi(v0.z) + bfhi(v1.z);
        a6 += bflo(v0.w) + bflo(v1.w); a7 += bfhi(v0.w) + bfhi(v1.w);
    }
    if (i < e) {
        uint4 v = xb4[csr[i] * 16 + ln];
        a0 += bflo(v.x); a1 += bfhi(v.x);
        a2 += bflo(v.y); a3 += bfhi(v.y);
        a4 += bflo(v.z); a5 += bfhi(v.z);
        a6 += bflo(v.w); a7 += bfhi(v.w);
    }
    float inv = 1.0f / (float)max(e - s, 1);
    uint4 o;
    o.x = ((unsigned)f2bf(a1 * inv) << 16) | f2bf(a0 * inv);
    o.y = ((unsigned)f2bf(a3 * inv) << 16) | f2bf(a2 * inv);
    o.z = ((unsigned)f2bf(a5 * inv) << 16) | f2bf(a4 * inv);
    o.w = ((unsigned)f2bf(a7 * inv) << 16) | f2bf(a6 * inv);
    agg4[node * 16 + ln] = o;
}

// ---------------- fused dual-GEMM layer, MFMA bf16 ----------------
__global__ __launch_bounds__(256) void fused_layer_mfma(const ushort* __restrict__ agg,
                                                        const ushort* __restrict__ xin,
                                                        ushort* __restrict__ xout,
                                                        const ushort* __restrict__ wpk,
                                                        const float* __restrict__ bias,
                                                        int residual) {
    __shared__ ushort sA[128 * RS];  // row r: [agg(128) | x(128) | pad(8)]
    int t = threadIdx.x;
    int node0 = blockIdx.x * 128;

    const uint4* aggv = (const uint4*)(agg + (size_t)node0 * DIM);
    const uint4* xv   = (const uint4*)(xin + (size_t)node0 * DIM);
    for (int i = t; i < 128 * 32; i += 256) {
        int r = i >> 5, c = i & 31;
        uint4 val = make_uint4(0u, 0u, 0u, 0u);
        if (node0 + r < N_NODES)
            val = (c < 16) ? aggv[r * 16 + c] : xv[r * 16 + (c - 16)];
        *(uint4*)&sA[r * RS + c * 8] = val;
    }
    __syncthreads();

    int wv = t >> 6, l = t & 63;
    int m0 = wv * 32;
    const ushort* arow = &sA[(m0 + (l & 31)) * RS];
    int khalf = (l >> 5) * 8;

    floatx16 acc0, acc1, acc2, acc3;
    for (int ii = 0; ii < 16; ii++) acc0[ii] = acc1[ii] = acc2[ii] = acc3[ii] = 0.f;

    const ushort* wl8 = wpk + (size_t)l * 8;
#pragma unroll
    for (int s2 = 0; s2 < 16; s2++) {
        int m = s2 >> 3, s = s2 & 7;
        short8 a = *(const short8*)(arow + m * 128 + s * 16 + khalf);
        size_t fb = (size_t)((m * 8 + s) * 4) * 512;
        short8 b0 = *(const short8*)(wl8 + fb);
        short8 b1 = *(const short8*)(wl8 + fb + 512);
        short8 b2 = *(const short8*)(wl8 + fb + 1024);
        short8 b3 = *(const short8*)(wl8 + fb + 1536);
        acc0 = __builtin_amdgcn_mfma_f32_32x32x16_bf16(a, b0, acc0, 0, 0, 0);
        acc1 = __builtin_amdgcn_mfma_f32_32x32x16_bf16(a, b1, acc1, 0, 0, 0);
        acc2 = __builtin_amdgcn_mfma_f32_32x32x16_bf16(a, b2, acc2, 0, 0, 0);
        acc3 = __builtin_amdgcn_mfma_f32_32x32x16_bf16(a, b3, acc3, 0, 0, 0);
    }

    int col = l & 31;
    int rbase = 4 * (l >> 5);
    floatx16 accs[4] = {acc0, acc1, acc2, acc3};
    for (int t4 = 0; t4 < 4; t4++) {
        int n = t4 * 32 + col;
        float bv = bias[n];
#pragma unroll
        for (int r = 0; r < 16; r++) {
            int row = (r & 3) + 8 * (r >> 2) + rbase;
            int gm = m0 + row;
            int gn = node0 + gm;
            if (gn >= N_NODES) continue;
            float v = accs[t4][r] + bv;
            v = (v >= 0.f) ? v : NEG_SLOPE * v;
            if (residual) v += bfraw2f(sA[gm * RS + 128 + n]);
            xout[(size_t)gn * DIM + n] = f2bf(v);
        }
    }
}

// ---------------- global mean pool, parallel segment-sum ----------------
// 128 nodes per block, 128 threads (one per dim); batch sorted -> few atomic flushes.
__global__ __launch_bounds__(128) void pool_partial(const ushort* __restrict__ xb,
                                                    const int* __restrict__ batch,
                                                    float* __restrict__ pooled) {
    int nb = blockIdx.x * 128;
    int ne = min(nb + 128, N_NODES);
    int d = threadIdx.x;
    int gcur = batch[nb];
    float acc = 0.f;
    for (int n = nb; n < ne; n++) {
        int g = batch[n];
        if (g != gcur) {
            atomicAdd(&pooled[gcur * DIM + d], acc);
            acc = 0.f;
            gcur = g;
        }
        acc += bfraw2f(xb[(size_t)n * DIM + d]);
    }
    atomicAdd(&pooled[gcur * DIM + d], acc);
}

__global__ void pool_final(const float* __restrict__ pooled,
                           const int* __restrict__ gstart,
                           float* __restrict__ out) {
    int i = blockIdx.x * blockDim.x + threadIdx.x;  // 32 blocks x 256
    if (i >= N_GRAPHS * DIM) return;
    int g = i >> 7;
    int cnt = gstart[g + 1] - gstart[g];
    out[i] = pooled[i] / (float)max(cnt, 1);
}

// ---------------- launch ----------------

extern "C" void kernel_launch(void* const* d_in, const int* in_sizes, int n_in,
                              void* d_out, int out_size, void* d_ws, size_t ws_size,
                              hipStream_t stream) {
    const float* x     = (const float*)d_in[0];
    const int*   ei    = (const int*)d_in[1];
    const int*   batch = (const int*)d_in[2];
    const float* Wl    = (const float*)d_in[3];
    const float* bl    = (const float*)d_in[4];
    const float* Wr    = (const float*)d_in[5];
    float* out = (float*)d_out;

    const int* esrc = ei;
    const int* edst = ei + N_EDGES;

    // workspace layout
    ushort* xb0  = (ushort*)d_ws;                         // [N,128] bf16
    ushort* xbuf = xb0 + (size_t)N_NODES * DIM;           // [N,128] bf16
    ushort* agg  = xbuf + (size_t)N_NODES * DIM;          // [N,128] bf16
    ushort* wpk  = agg + (size_t)N_NODES * DIM;           // [4][2][128*128] bf16
    int* deg    = (int*)(wpk + (size_t)N_LAYERS * 2 * DIM * DIM);
    int* fill   = deg + N_NODES;
    int* csr    = fill + N_NODES;
    int* rp     = csr + N_EDGES;
    int* gstart = rp + (N_NODES + 1);
    int* bsum   = gstart + (N_GRAPHS + 1);
    float* pooled = (float*)(bsum + NB_SCAN);             // [G,128] fp32

    // zero deg+fill (adjacent) and pooled
    zero_ints<<<(2 * N_NODES + 255) / 256, 256, 0, stream>>>(deg, 2 * N_NODES);
    zero_ints<<<(N_GRAPHS * DIM + 255) / 256, 256, 0, stream>>>((int*)pooled, N_GRAPHS * DIM);

    convert_x<<<(N_NODES * DIM / 8 + 255) / 256, 256, 0, stream>>>((const float4*)x, (uint4*)xb0);
    pack_w<<<dim3(32, 2, 4), 64, 0, stream>>>(Wl, Wr, wpk);
    count_deg<<<(N_EDGES + 255) / 256, 256, 0, stream>>>(edst, deg);

    scan_pass1<<<NB_SCAN, 256, 0, stream>>>(deg, bsum);
    scan_pass2<<<1, 256, 0, stream>>>(bsum);
    scan_pass3<<<NB_SCAN, 256, 0, stream>>>(deg, bsum, rp);

    fill_csr<<<(N_EDGES + 255) / 256, 256, 0, stream>>>(esrc, edst, rp, fill, csr);
    graph_start<<<(N_NODES + 255) / 256, 256, 0, stream>>>(batch, gstart);

    int agg_blocks = (N_NODES + 15) / 16;
    int gemm_blocks = (N_NODES + 127) / 128;
    for (int l = 0; l < N_LAYERS; l++) {
        const ushort* xin = (l == 0) ? xb0 : xbuf;
        agg_mean_bf16<<<agg_blocks, 256, 0, stream>>>((const uint4*)xin, rp, csr, (uint4*)agg);
        fused_layer_mfma<<<gemm_blocks, 256, 0, stream>>>(
            agg, xin, xbuf, wpk + (size_t)l * 2 * DIM * DIM,
            bl + (size_t)l * DIM, (l >= 2) ? 1 : 0);
    }

    pool_partial<<<(N_NODES + 127) / 128, 128, 0, stream>>>(xbuf, batch, pooled);
    pool_final<<<(N_GRAPHS * DIM + 255) / 256, 256, 0, stream>>>(pooled, gstart, out);
}

// Round 5
// 374.984 us; speedup vs baseline: 2.0341x; 1.0094x over previous
//
#include <hip/hip_runtime.h>

#define N_NODES 50000
#define N_EDGES 600000
#define DIM 128
#define N_LAYERS 4
#define N_GRAPHS 64
#define NEG_SLOPE 0.01f
#define NB_SCAN ((N_NODES + 255) / 256)  // 196 blocks
#define RS 264  // LDS row stride in bf16 elems: 256 data + 8 pad (16B)

typedef __attribute__((ext_vector_type(8))) short short8;
typedef __attribute__((ext_vector_type(16))) float floatx16;

__device__ __forceinline__ unsigned short f2bf(float f) {
    union { float f; unsigned u; } c; c.f = f;
    unsigned u = c.u;
    unsigned r = (u + 0x7FFFu + ((u >> 16) & 1u)) >> 16;
    return (unsigned short)r;
}
__device__ __forceinline__ float bfraw2f(unsigned short b) {
    union { unsigned u; float f; } c; c.u = ((unsigned)b) << 16;
    return c.f;
}
__device__ __forceinline__ float bflo(unsigned u) {
    union { unsigned u; float f; } c; c.u = u << 16; return c.f;
}
__device__ __forceinline__ float bfhi(unsigned u) {
    union { unsigned u; float f; } c; c.u = u & 0xFFFF0000u; return c.f;
}

// ---------------- utility kernels ----------------

__global__ void zero_ints(int* p, int n) {
    int i = blockIdx.x * blockDim.x + threadIdx.x;
    if (i < n) p[i] = 0;
}

// convert fp32 x -> bf16 (8 elems per thread)
__global__ void convert_x(const float4* __restrict__ x, uint4* __restrict__ xb) {
    int i = blockIdx.x * blockDim.x + threadIdx.x;  // chunk of 8 floats
    if (i >= N_NODES * DIM / 8) return;
    float4 a = x[i * 2], b = x[i * 2 + 1];
    uint4 o;
    o.x = ((unsigned)f2bf(a.y) << 16) | f2bf(a.x);
    o.y = ((unsigned)f2bf(a.w) << 16) | f2bf(a.z);
    o.z = ((unsigned)f2bf(b.y) << 16) | f2bf(b.x);
    o.w = ((unsigned)f2bf(b.w) << 16) | f2bf(b.z);
    xb[i] = o;
}

// pack weights into MFMA B-fragment order (bf16), for v_mfma_f32_32x32x16_bf16.
// B[k][n] = W[n][k]. Fragment (layer, m, s, t): lane l holds B[s*16+(l>>5)*8+j][t*32+(l&31)], j=0..7.
__global__ void pack_w(const float* __restrict__ Wl, const float* __restrict__ Wr,
                       ushort* __restrict__ wpk) {
    int s = blockIdx.x >> 2, t = blockIdx.x & 3;
    int m = blockIdx.y, layer = blockIdx.z;
    int l = threadIdx.x;  // 64 lanes
    const float* W = ((m == 0) ? Wl : Wr) + (size_t)layer * DIM * DIM;
    int n = t * 32 + (l & 31);
    int kb = s * 16 + (l >> 5) * 8;
    size_t off = ((((size_t)(layer * 2 + m) * 8 + s) * 4 + t) * 64 + l) * 8;
    for (int j = 0; j < 8; j++)
        wpk[off + j] = f2bf(W[n * DIM + kb + j]);
}

__global__ void count_deg(const int* __restrict__ dst, int* deg) {
    int e = blockIdx.x * blockDim.x + threadIdx.x;
    if (e < N_EDGES) atomicAdd(&deg[dst[e]], 1);
}

// ---------------- 3-pass exclusive scan of deg -> rp ----------------
__global__ void scan_pass1(const int* __restrict__ deg, int* __restrict__ bsum) {
    int i = blockIdx.x * 256 + threadIdx.x;
    int v = (i < N_NODES) ? deg[i] : 0;
    for (int off = 32; off > 0; off >>= 1) v += __shfl_down(v, off, 64);
    __shared__ int ws[4];
    int lane = threadIdx.x & 63, w = threadIdx.x >> 6;
    if (lane == 0) ws[w] = v;
    __syncthreads();
    if (threadIdx.x == 0) bsum[blockIdx.x] = ws[0] + ws[1] + ws[2] + ws[3];
}

__global__ void scan_pass2(int* __restrict__ bsum) {
    __shared__ int sm[256];
    int t = threadIdx.x;
    int v = (t < NB_SCAN) ? bsum[t] : 0;
    sm[t] = v;
    __syncthreads();
    for (int off = 1; off < 256; off <<= 1) {
        int u = (t >= off) ? sm[t - off] : 0;
        __syncthreads();
        sm[t] += u;
        __syncthreads();
    }
    if (t < NB_SCAN) bsum[t] = sm[t] - v;
}

__global__ void scan_pass3(const int* __restrict__ deg, const int* __restrict__ bsum,
                           int* __restrict__ rp) {
    int i = blockIdx.x * 256 + threadIdx.x;
    int v = (i < N_NODES) ? deg[i] : 0;
    int lane = threadIdx.x & 63, w = threadIdx.x >> 6;
    int s = v;
    for (int off = 1; off < 64; off <<= 1) {
        int t = __shfl_up(s, off, 64);
        if (lane >= off) s += t;
    }
    __shared__ int ws[4];
    if (lane == 63) ws[w] = s;
    __syncthreads();
    int wo = 0;
    for (int k = 0; k < 4; k++) wo += (k < w) ? ws[k] : 0;
    int incl = s + wo + bsum[blockIdx.x];
    if (i < N_NODES) rp[i + 1] = incl;
    if (i == 0) rp[0] = 0;
}

__global__ void fill_csr(const int* __restrict__ src, const int* __restrict__ dst,
                         const int* __restrict__ rp, int* __restrict__ fill,
                         int* __restrict__ csr) {
    int e = blockIdx.x * blockDim.x + threadIdx.x;
    if (e >= N_EDGES) return;
    int d = dst[e];
    int pos = atomicAdd(&fill[d], 1);
    csr[rp[d] + pos] = src[e];
}

__global__ void graph_start(const int* __restrict__ batch, int* __restrict__ gstart) {
    int i = blockIdx.x * blockDim.x + threadIdx.x;
    if (i >= N_NODES) return;
    int b = batch[i];
    if (i == 0) {
        for (int g = 0; g <= b; g++) gstart[g] = 0;
    } else {
        int p = batch[i - 1];
        for (int g = p + 1; g <= b; g++) gstart[g] = i;
    }
    if (i == N_NODES - 1) {
        for (int g = b + 1; g <= N_GRAPHS; g++) gstart[g] = N_NODES;
    }
}

// ---------------- aggregation: one wave per node, MLP=8 ----------------
// Lane covers 2 dims (uint = 2 bf16); 64 lanes = one coalesced 256B row.
// Neighbor indices vector-loaded once per 64, broadcast via __shfl (no divergence).
__global__ __launch_bounds__(256) void agg_mean_wave(const uint* __restrict__ x32,
                                                     const int* __restrict__ rp,
                                                     const int* __restrict__ csr,
                                                     uint* __restrict__ agg32) {
    int wv = threadIdx.x >> 6, lane = threadIdx.x & 63;
    int node = blockIdx.x * 4 + wv;
    if (node >= N_NODES) return;
    int s = rp[node], e = rp[node + 1];
    float a0 = 0.f, a1 = 0.f;
    for (int base = s; base < e; base += 64) {
        int cnt = min(64, e - base);
        unsigned myidx = (base + lane < e) ? (unsigned)csr[base + lane] : 0u;
        for (int j = 0; j < cnt; j += 8) {
            int c2 = min(8, cnt - j);
            unsigned v[8];
#pragma unroll
            for (int k = 0; k < 8; k++) {
                unsigned idx = __shfl(myidx, j + k, 64);
                v[k] = (k < c2) ? x32[(size_t)idx * 64 + lane] : 0u;
            }
#pragma unroll
            for (int k = 0; k < 8; k++) { a0 += bflo(v[k]); a1 += bfhi(v[k]); }
        }
    }
    float inv = 1.0f / (float)max(e - s, 1);
    unsigned o = ((unsigned)f2bf(a1 * inv) << 16) | f2bf(a0 * inv);
    agg32[(size_t)node * 64 + lane] = o;
}

// ---------------- fused dual-GEMM layer, MFMA bf16 ----------------
__global__ __launch_bounds__(256) void fused_layer_mfma(const ushort* __restrict__ agg,
                                                        const ushort* __restrict__ xin,
                                                        ushort* __restrict__ xout,
                                                        const ushort* __restrict__ wpk,
                                                        const float* __restrict__ bias,
                                                        int residual) {
    __shared__ ushort sA[128 * RS];  // row r: [agg(128) | x(128) | pad(8)]
    int t = threadIdx.x;
    int node0 = blockIdx.x * 128;

    const uint4* aggv = (const uint4*)(agg + (size_t)node0 * DIM);
    const uint4* xv   = (const uint4*)(xin + (size_t)node0 * DIM);
    for (int i = t; i < 128 * 32; i += 256) {
        int r = i >> 5, c = i & 31;
        uint4 val = make_uint4(0u, 0u, 0u, 0u);
        if (node0 + r < N_NODES)
            val = (c < 16) ? aggv[r * 16 + c] : xv[r * 16 + (c - 16)];
        *(uint4*)&sA[r * RS + c * 8] = val;
    }
    __syncthreads();

    int wv = t >> 6, l = t & 63;
    int m0 = wv * 32;
    const ushort* arow = &sA[(m0 + (l & 31)) * RS];
    int khalf = (l >> 5) * 8;

    floatx16 acc0, acc1, acc2, acc3;
    for (int ii = 0; ii < 16; ii++) acc0[ii] = acc1[ii] = acc2[ii] = acc3[ii] = 0.f;

    const ushort* wl8 = wpk + (size_t)l * 8;
#pragma unroll
    for (int s2 = 0; s2 < 16; s2++) {
        int m = s2 >> 3, s = s2 & 7;
        short8 a = *(const short8*)(arow + m * 128 + s * 16 + khalf);
        size_t fb = (size_t)((m * 8 + s) * 4) * 512;
        short8 b0 = *(const short8*)(wl8 + fb);
        short8 b1 = *(const short8*)(wl8 + fb + 512);
        short8 b2 = *(const short8*)(wl8 + fb + 1024);
        short8 b3 = *(const short8*)(wl8 + fb + 1536);
        acc0 = __builtin_amdgcn_mfma_f32_32x32x16_bf16(a, b0, acc0, 0, 0, 0);
        acc1 = __builtin_amdgcn_mfma_f32_32x32x16_bf16(a, b1, acc1, 0, 0, 0);
        acc2 = __builtin_amdgcn_mfma_f32_32x32x16_bf16(a, b2, acc2, 0, 0, 0);
        acc3 = __builtin_amdgcn_mfma_f32_32x32x16_bf16(a, b3, acc3, 0, 0, 0);
    }

    int col = l & 31;
    int rbase = 4 * (l >> 5);
    floatx16 accs[4] = {acc0, acc1, acc2, acc3};
    for (int t4 = 0; t4 < 4; t4++) {
        int n = t4 * 32 + col;
        float bv = bias[n];
#pragma unroll
        for (int r = 0; r < 16; r++) {
            int row = (r & 3) + 8 * (r >> 2) + rbase;
            int gm = m0 + row;
            int gn = node0 + gm;
            if (gn >= N_NODES) continue;
            float v = accs[t4][r] + bv;
            v = (v >= 0.f) ? v : NEG_SLOPE * v;
            if (residual) v += bfraw2f(sA[gm * RS + 128 + n]);
            xout[(size_t)gn * DIM + n] = f2bf(v);
        }
    }
}

// ---------------- global mean pool, parallel segment-sum ----------------
__global__ __launch_bounds__(128) void pool_partial(const ushort* __restrict__ xb,
                                                    const int* __restrict__ batch,
                                                    float* __restrict__ pooled) {
    int nb = blockIdx.x * 128;
    int ne = min(nb + 128, N_NODES);
    int d = threadIdx.x;
    int gcur = batch[nb];
    float acc = 0.f;
    for (int n = nb; n < ne; n++) {
        int g = batch[n];
        if (g != gcur) {
            atomicAdd(&pooled[gcur * DIM + d], acc);
            acc = 0.f;
            gcur = g;
        }
        acc += bfraw2f(xb[(size_t)n * DIM + d]);
    }
    atomicAdd(&pooled[gcur * DIM + d], acc);
}

__global__ void pool_final(const float* __restrict__ pooled,
                           const int* __restrict__ gstart,
                           float* __restrict__ out) {
    int i = blockIdx.x * blockDim.x + threadIdx.x;  // 32 blocks x 256
    if (i >= N_GRAPHS * DIM) return;
    int g = i >> 7;
    int cnt = gstart[g + 1] - gstart[g];
    out[i] = pooled[i] / (float)max(cnt, 1);
}

// ---------------- launch ----------------

extern "C" void kernel_launch(void* const* d_in, const int* in_sizes, int n_in,
                              void* d_out, int out_size, void* d_ws, size_t ws_size,
                              hipStream_t stream) {
    const float* x     = (const float*)d_in[0];
    const int*   ei    = (const int*)d_in[1];
    const int*   batch = (const int*)d_in[2];
    const float* Wl    = (const float*)d_in[3];
    const float* bl    = (const float*)d_in[4];
    const float* Wr    = (const float*)d_in[5];
    float* out = (float*)d_out;

    const int* esrc = ei;
    const int* edst = ei + N_EDGES;

    // workspace layout
    ushort* xb0  = (ushort*)d_ws;                         // [N,128] bf16
    ushort* xbuf = xb0 + (size_t)N_NODES * DIM;           // [N,128] bf16
    ushort* agg  = xbuf + (size_t)N_NODES * DIM;          // [N,128] bf16
    ushort* wpk  = agg + (size_t)N_NODES * DIM;           // [4][2][128*128] bf16
    int* deg    = (int*)(wpk + (size_t)N_LAYERS * 2 * DIM * DIM);
    int* fill   = deg + N_NODES;
    int* csr    = fill + N_NODES;
    int* rp     = csr + N_EDGES;
    int* gstart = rp + (N_NODES + 1);
    int* bsum   = gstart + (N_GRAPHS + 1);
    float* pooled = (float*)(bsum + NB_SCAN);             // [G,128] fp32

    zero_ints<<<(2 * N_NODES + 255) / 256, 256, 0, stream>>>(deg, 2 * N_NODES);
    zero_ints<<<(N_GRAPHS * DIM + 255) / 256, 256, 0, stream>>>((int*)pooled, N_GRAPHS * DIM);

    convert_x<<<(N_NODES * DIM / 8 + 255) / 256, 256, 0, stream>>>((const float4*)x, (uint4*)xb0);
    pack_w<<<dim3(32, 2, 4), 64, 0, stream>>>(Wl, Wr, wpk);
    count_deg<<<(N_EDGES + 255) / 256, 256, 0, stream>>>(edst, deg);

    scan_pass1<<<NB_SCAN, 256, 0, stream>>>(deg, bsum);
    scan_pass2<<<1, 256, 0, stream>>>(bsum);
    scan_pass3<<<NB_SCAN, 256, 0, stream>>>(deg, bsum, rp);

    fill_csr<<<(N_EDGES + 255) / 256, 256, 0, stream>>>(esrc, edst, rp, fill, csr);
    graph_start<<<(N_NODES + 255) / 256, 256, 0, stream>>>(batch, gstart);

    int agg_blocks = (N_NODES + 3) / 4;   // one wave per node
    int gemm_blocks = (N_NODES + 127) / 128;
    for (int l = 0; l < N_LAYERS; l++) {
        const ushort* xin = (l == 0) ? xb0 : xbuf;
        agg_mean_wave<<<agg_blocks, 256, 0, stream>>>((const uint*)xin, rp, csr, (uint*)agg);
        fused_layer_mfma<<<gemm_blocks, 256, 0, stream>>>(
            agg, xin, xbuf, wpk + (size_t)l * 2 * DIM * DIM,
            bl + (size_t)l * DIM, (l >= 2) ? 1 : 0);
    }

    pool_partial<<<(N_NODES + 127) / 128, 128, 0, stream>>>(xbuf, batch, pooled);
    pool_final<<<(N_GRAPHS * DIM + 255) / 256, 256, 0, stream>>>(pooled, gstart, out);
}